// Round 15
// baseline (216.827 us; speedup 1.0000x reference)
//
#include <hip/hip_runtime.h>
#include <hip/hip_fp16.h>

#define Q_TOT 1024
#define T_TOT 256
#define NPTS  100
#define KD    300
#define EPSV  1e-6f

#define KSTEPS 10            // 10 * 32 = 320 >= 300 (zero-padded K)
#define MT     14            // 7 M-tiles fwd + 7 bwd

typedef _Float16 f16;
typedef _Float16 f16x8 __attribute__((ext_vector_type(8)));
typedef float    f32x4 __attribute__((ext_vector_type(4)));
#define MFMA16 __builtin_amdgcn_mfma_f32_16x16x32_f16

// ws layout (floats):
//   [0,1024)       p2[q] = sum(pred_q^2)
//   [1024,1280)    v2[t] = sum(tgt_t^2)
//   [1280,+327680) pfrag: B-fragments, f16x8 idx = ((nt*10+ks)*2+s)*64+lane
#define WS_PF 1280

// ---------------------------------------------------------------------------
// Prep (single small kernel, 320 blocks x 256):
//  - each thread writes one pfrag f16x8 (i = 0..81919)
//  - each WAVE reduces one p2/v2 row via shuffle (kills R14's serial
//    300-load latency chains; reorder is argmin-safe: p2+v2 is common-mode
//    across all variants of a (t,q) pair)
// ---------------------------------------------------------------------------
__global__ __launch_bounds__(256) void prep_all(const float* __restrict__ preds,
                                                const float* __restrict__ tgt,
                                                float* __restrict__ ws)
{
    const int i = blockIdx.x*256 + threadIdx.x;      // exactly 81920 threads
    {
        int lane = i & 63;
        int r    = i >> 6;
        int s    = r & 1;  r >>= 1;
        int ks   = r % KSTEPS;
        int nt   = r / KSTEPS;
        int q    = nt*16 + (lane & 15);
        int kb   = ks*32 + (lane >> 4)*8;
        f16x8 v;
        #pragma unroll
        for (int j = 0; j < 8; ++j) {
            int k = kb + j;
            float x = (k < KD) ? preds[q*KD + k] : 0.f;
            f16 h = (f16)x;
            v[j] = s ? (f16)(x - (float)h) : h;
        }
        ((f16x8*)(ws + WS_PF))[i] = v;
    }
    // p2/v2: one row per wave (320 blocks x 4 waves = 1280 rows)
    const int row  = blockIdx.x*4 + (threadIdx.x >> 6);
    const int lane = threadIdx.x & 63;
    const float* base = (row < 1024) ? preds + row*KD : tgt + (row-1024)*KD;
    float s = 0.f;
    for (int k = lane; k < KD; k += 64) s = fmaf(base[k], base[k], s);
    #pragma unroll
    for (int m = 1; m < 64; m <<= 1) s += __shfl_xor(s, m, 64);
    if (lane == 0) ws[row] = s;
}

// ---------------------------------------------------------------------------
// One sweep: NMT M-tiles x 8 N-tiles, K=320.  Phase 1: all 512 threads
// compute this sweep's A-fragments (f16 hi/lo split, pre-swizzled operand
// order) into LDS.  Phase 2: MFMA with lane-contiguous conflict-free
// ds_read_b128 A-loads + L2-resident global B-loads.  No afrag HBM buffer.
// ---------------------------------------------------------------------------
template<int MTB, int NMT>
__device__ __forceinline__ void sweep(f16x8* __restrict__ asweep,
                                      const float* __restrict__ extF,
                                      const float* __restrict__ extR,
                                      const f16x8* __restrict__ pfrag,
                                      int tid, int ntb, int lane, int col, int rg,
                                      float v2t, const float (&p2v)[8],
                                      float (&minD)[8], int (&minI)[8],
                                      float (*sopen)[1024])
{
    // Phase 1: A-fragments for M-tiles MTB..MTB+NMT-1 into LDS
    for (int j = tid; j < NMT*KSTEPS*2*64; j += 512) {
        int jl = j & 63;
        int r  = j >> 6;
        int s  = r & 1;  r >>= 1;
        int ks = r % KSTEPS;
        int h  = r / KSTEPS;
        int mt = MTB + h;
        int jc = jl & 15;
        int jg = jl >> 4;
        int mtp = (mt < 7) ? mt : mt-7;
        int a   = mtp*16 + jc;
        const float* ext = (mt < 7) ? extF : extR;
        f16x8 v;
        #pragma unroll
        for (int jj = 0; jj < 8; ++jj) {
            int k = ks*32 + jg*8 + jj;
            float x = (a < 100 && k < KD) ? ext[300 - 3*a + k] : 0.f;
            f16 hh = (f16)x;
            v[jj] = s ? (f16)(x - (float)hh) : hh;
        }
        asweep[j] = v;
    }
    __syncthreads();

    // Phase 2: MFMA accumulation (order identical to R11..R14 -> same d2)
    f32x4 acc[NMT][8];
    #pragma unroll
    for (int h = 0; h < NMT; ++h)
        #pragma unroll
        for (int nt = 0; nt < 8; ++nt) acc[h][nt] = (f32x4){0.f,0.f,0.f,0.f};

    #pragma clang loop unroll(disable)
    for (int ks = 0; ks < KSTEPS; ++ks) {
        f16x8 ah[NMT], alo[NMT];
        #pragma unroll
        for (int h = 0; h < NMT; ++h) {
            const int i = ((h*KSTEPS + ks)*2)*64 + lane;
            ah[h]  = asweep[i];
            alo[h] = asweep[i + 64];
        }
        #pragma unroll
        for (int nt = 0; nt < 8; ++nt) {
            const int fi = ((ntb+nt)*KSTEPS + ks)*128 + lane;
            f16x8 bh = pfrag[fi];
            f16x8 bl = pfrag[fi + 64];
            #pragma unroll
            for (int h = 0; h < NMT; ++h) {
                acc[h][nt] = MFMA16(ah[h],  bh, acc[h][nt], 0,0,0);
                acc[h][nt] = MFMA16(ah[h],  bl, acc[h][nt], 0,0,0);
                acc[h][nt] = MFMA16(alo[h], bh, acc[h][nt], 0,0,0);
            }
        }
    }
    __syncthreads();   // all waves done reading asweep before next overwrite

    // Fold D -> d2 -> running (min, argmin), ascending v within lane.
    #pragma unroll
    for (int h = 0; h < NMT; ++h) {
        const int mt   = MTB + h;
        const int mtp  = (mt < 7) ? mt : mt-7;
        const int voff = (mt < 7) ? 0 : 100;
        const int ab   = mtp*16 + rg*4;
        #pragma unroll
        for (int nt = 0; nt < 8; ++nt) {
            const float s2 = v2t + p2v[nt];
            #pragma unroll
            for (int r = 0; r < 4; ++r) {
                const int al = ab + r;
                if (al < 100) {
                    float d2 = fmaxf(fmaf(-2.f, acc[h][nt][r], s2), 0.f) * 0.01f;
                    int vlog = voff + al;
                    if (d2 < minD[nt]) { minD[nt] = d2; minI[nt] = vlog; }
                    if (al == 0) sopen[voff ? 1 : 0][(ntb+nt)*16 + col] = d2;
                }
            }
        }
    }
}

// ---------------------------------------------------------------------------
// One block = one target t x all 1024 queries.  8 waves x 8 N-tiles each.
// LDS: asweep 80K + ext 4.8K + red 32K + sopen 8K = 125 KB.
// ---------------------------------------------------------------------------
__global__ __launch_bounds__(512) void matcher_mfma(
    const float* __restrict__ ws,      // p2 / v2 / pfrag
    const float* __restrict__ tgt,     // [256][300]
    const float* __restrict__ plog,    // [1024][2]
    const float* __restrict__ ptyp,    // [1024][4]
    const float* __restrict__ clog,    // [1024][2]
    const int*   __restrict__ labels,  // [256]
    const int*   __restrict__ iscl,    // [256]
    const float* __restrict__ clw,     // [256]
    float* __restrict__ out)           // [2][1024][256] flat fp32
{
    __shared__ __align__(16) f16x8 asweep[4*KSTEPS*2*64];  // 80 KB
    __shared__ float extF[600], extR[600];
    __shared__ float redD[4096];
    __shared__ int   redI[4096];
    __shared__ float sopen[2][1024];

    const int t    = blockIdx.x;
    const int tid  = threadIdx.x;
    const int lane = tid & 63;
    const int w    = tid >> 6;          // wave 0..7 -> N-tiles w*8..w*8+7
    const int col  = lane & 15;
    const int rg   = lane >> 4;

    // Stage doubled fwd/bwd target curves
    const float* tg = tgt + t*KD;
    for (int x = tid; x < 600; x += 512) {
        int m = (x >= 300) ? x-300 : x;
        extF[x] = tg[m];
        int jj = m / 3, c3 = m - 3*jj;
        extR[x] = tg[(NPTS-1-jj)*3 + c3];
    }

    const float v2t = ws[1024 + t];
    const int ntb = w*8;
    float p2v[8];
    #pragma unroll
    for (int nt = 0; nt < 8; ++nt) p2v[nt] = ws[(ntb+nt)*16 + col];

    const f16x8* __restrict__ pfrag = (const f16x8*)(ws + WS_PF);
    __syncthreads();   // ext ready

    float minD[8]; int minI[8];
    #pragma unroll
    for (int nt = 0; nt < 8; ++nt) { minD[nt] = 3.4028235e38f; minI[nt] = 0; }

    sweep< 0,4>(asweep, extF, extR, pfrag, tid, ntb, lane, col, rg, v2t, p2v, minD, minI, sopen);
    sweep< 4,4>(asweep, extF, extR, pfrag, tid, ntb, lane, col, rg, v2t, p2v, minD, minI, sopen);
    sweep< 8,4>(asweep, extF, extR, pfrag, tid, ntb, lane, col, rg, v2t, p2v, minD, minI, sopen);
    sweep<12,2>(asweep, extF, extR, pfrag, tid, ntb, lane, col, rg, v2t, p2v, minD, minI, sopen);

    #pragma unroll
    for (int nt = 0; nt < 8; ++nt) {
        redD[(w*8 + nt)*64 + lane] = minD[nt];
        redI[(w*8 + nt)*64 + lane] = minI[nt];
    }
    __syncthreads();

    // Epilogue: cross-row-group reduce (lexicographic (d,v) = first occurrence),
    // then cost-class terms; 2 queries per thread.
    for (int q = tid; q < Q_TOT; q += 512) {
        const int ww  = q >> 7;
        const int ntl = (q >> 4) & 7;
        const int cc  = q & 15;
        const int base = (ww*8 + ntl)*64 + cc;
        float bd = redD[base]; int bi = redI[base];
        #pragma unroll
        for (int g = 1; g < 4; ++g) {
            float d = redD[base + g*16]; int i = redI[base + g*16];
            if (d < bd || (d == bd && i < bi)) { bd = d; bi = i; }
        }
        int mapped = (bi <= NPTS-1) ? bi : (2*NPTS-1 - bi);
        float od   = fminf(sopen[0][q], sopen[1][q]);
        int   isc  = iscl[t];
        float geom = isc ? bd : od;
        int   ido  = isc ? mapped : 0;
        geom *= clw[t];

        float t0 = ptyp[q*4+0], t1 = ptyp[q*4+1];
        float t2 = ptyp[q*4+2], t3 = ptyp[q*4+3];
        float mx = fmaxf(fmaxf(t0,t1), fmaxf(t2,t3));
        float e0 = expf(t0-mx), e1 = expf(t1-mx), e2 = expf(t2-mx), e3 = expf(t3-mx);
        float rs = 1.0f/(e0+e1+e2+e3);
        int lab  = labels[t];
        float el = (lab == 0) ? e0 : (lab == 1) ? e1 : (lab == 2) ? e2 : e3;
        float cost = -logf(el*rs + EPSV);
        float v0 = plog[q*2+0], v1 = plog[q*2+1];
        cost += -logf(1.0f/(1.0f + expf(v1-v0)) + EPSV);
        float c0 = clog[q*2+0], c1 = clog[q*2+1];
        float pc = isc ? (1.0f/(1.0f + expf(c0-c1))) : (1.0f/(1.0f + expf(c1-c0)));
        cost += -logf(pc + EPSV);

        float C = geom + cost;
        out[q*T_TOT + t]               = C;
        out[Q_TOT*T_TOT + q*T_TOT + t] = (float)ido;
    }
}

extern "C" void kernel_launch(void* const* d_in, const int* in_sizes, int n_in,
                              void* d_out, int out_size, void* d_ws, size_t ws_size,
                              hipStream_t stream)
{
    const float* preds  = (const float*)d_in[0];  // pred_curve_points (1,1024,100,3)
    const float* plog   = (const float*)d_in[1];  // pred_curve_logits (1,1024,2)
    const float* ptyp   = (const float*)d_in[2];  // pred_curve_type   (1,1024,4)
    const float* clog   = (const float*)d_in[3];  // closed_curve_logits (1,1024,2)
    const float* tgt    = (const float*)d_in[4];  // tgt_curve_points  (256,100,3)
    const int*   labels = (const int*)d_in[5];    // tgt_labels (256)
    const int*   iscl   = (const int*)d_in[6];    // tgt_is_closed (256)
    const float* clw    = (const float*)d_in[7];  // curve_length_weighting (256)
    float* out = (float*)d_out;
    float* ws  = (float*)d_ws;    // 1280 + 327680 floats = 1.32 MB

    prep_all    <<<dim3(320),   dim3(256), 0, stream>>>(preds, tgt, ws);
    matcher_mfma<<<dim3(T_TOT), dim3(512), 0, stream>>>(
        ws, tgt, plog, ptyp, clog, labels, iscl, clw, out);
}

// Round 16
// 199.113 us; speedup vs baseline: 1.0890x; 1.0890x over previous
//
#include <hip/hip_runtime.h>
#include <hip/hip_fp16.h>

#define Q_TOT 1024
#define T_TOT 256
#define NPTS  100
#define KD    300
#define EPSV  1e-6f

#define KSTEPS 10            // 10 * 32 = 320 >= 300 (zero-padded K)
#define MT     14            // 7 M-tiles fwd + 7 bwd

typedef _Float16 f16;
typedef _Float16 f16x8 __attribute__((ext_vector_type(8)));
typedef float    f32x4 __attribute__((ext_vector_type(4)));
#define MFMA16 __builtin_amdgcn_mfma_f32_16x16x32_f16

// ws layout (floats):
//   [0,1024)       p2[q]; [1024,1280) v2[t]
//   [1280,+327680) pfrag: B-fragments, f16x8 idx = ((nt*10+ks)*2+s)*64+lane
//   [WS_AF,...)    afrag: per-target A-fragments (73.4 MB), f16x8 idx =
//                  t*17920 + ((mt*10+ks)*2+s)*64+lane
#define WS_PF 1280
#define WS_AF (WS_PF + 81920*4)
#define AFRAG_PER_T (MT*KSTEPS*2*64)

// ---------------------------------------------------------------------------
// Fused prep, one block per target: (a) afrag via LDS-staged ext curves,
// (b) 320-f16x8 pfrag slice, (c) 5 p2/v2 rows via wave-shuffle reduction
// (reorder argmin-safe: p2+v2 is common-mode across a (t,q) pair's variants).
// ---------------------------------------------------------------------------
__global__ __launch_bounds__(512) void prep_all(const float* __restrict__ preds,
                                                const float* __restrict__ tgt,
                                                float* __restrict__ ws)
{
    __shared__ float extF[600], extR[600];
    const int t   = blockIdx.x;
    const int tid = threadIdx.x;
    const float* tg = tgt + t*KD;

    // (b) pfrag slice: 81920 / 256 blocks = 320 per block
    if (tid < 320) {
        int idx  = t*320 + tid;
        int lane = idx & 63;
        int r    = idx >> 6;
        int s    = r & 1;  r >>= 1;
        int ks   = r % KSTEPS;
        int nt   = r / KSTEPS;
        int q    = nt*16 + (lane & 15);
        int kb   = ks*32 + (lane >> 4)*8;
        f16x8 v;
        #pragma unroll
        for (int j = 0; j < 8; ++j) {
            int k = kb + j;
            float x = (k < KD) ? preds[q*KD + k] : 0.f;
            f16 h = (f16)x;
            v[j] = s ? (f16)(x - (float)h) : h;
        }
        ((f16x8*)(ws + WS_PF))[idx] = v;
    }

    // (c) p2/v2: 5 rows per block, one per wave, shuffle-reduced
    {
        const int wv   = tid >> 6;
        const int lane = tid & 63;
        if (wv < 5) {
            const int row = t*5 + wv;           // 256*5 = 1280 rows
            const float* base = (row < 1024) ? preds + row*KD : tgt + (row-1024)*KD;
            float s = 0.f;
            for (int k = lane; k < KD; k += 64) s = fmaf(base[k], base[k], s);
            #pragma unroll
            for (int m = 1; m < 64; m <<= 1) s += __shfl_xor(s, m, 64);
            if (lane == 0) ws[row] = s;
        }
    }

    // ext staging
    for (int x = tid; x < 600; x += 512) {
        int m = (x >= 300) ? x-300 : x;
        extF[x] = tg[m];
        int jj = m / 3, c3 = m - 3*jj;
        extR[x] = tg[(NPTS-1-jj)*3 + c3];
    }
    __syncthreads();

    // (a) A-fragments in exact MFMA operand order
    f16x8* outp = (f16x8*)(ws + WS_AF) + t*AFRAG_PER_T;
    for (int j = tid; j < AFRAG_PER_T; j += 512) {
        int lane = j & 63;
        int r    = j >> 6;
        int s    = r & 1;  r >>= 1;
        int ks   = r % KSTEPS;
        int mt   = r / KSTEPS;
        int col  = lane & 15;
        int rg   = lane >> 4;
        int mtp  = (mt < 7) ? mt : mt-7;
        int a    = mtp*16 + col;
        const float* ext = (mt < 7) ? extF : extR;
        f16x8 v;
        #pragma unroll
        for (int jj = 0; jj < 8; ++jj) {
            int k = ks*32 + rg*8 + jj;
            float x = (a < 100 && k < KD) ? ext[300 - 3*a + k] : 0.f;
            f16 h = (f16)x;
            v[jj] = s ? (f16)(x - (float)h) : h;
        }
        outp[j] = v;
    }
}

// ---------------------------------------------------------------------------
// One sweep: NMT M-tiles x 4 N-tiles.  acc[NMT][4] = 64 regs -- the only
// pressure level that has never spilled (R11).  B re-read once per sweep.
// ---------------------------------------------------------------------------
template<int MTB, int NMT>
__device__ __forceinline__ void sweep(const f16x8* __restrict__ afrag,
                                      const f16x8* __restrict__ pfrag,
                                      int ntg0, int lane, int col, int rg,
                                      float v2t, const float (&p2v)[4],
                                      float (&minD)[4], int (&minI)[4],
                                      float (*sopen)[512], int ntl0)
{
    f32x4 acc[NMT][4];
    #pragma unroll
    for (int h = 0; h < NMT; ++h)
        #pragma unroll
        for (int nt = 0; nt < 4; ++nt) acc[h][nt] = (f32x4){0.f,0.f,0.f,0.f};

    #pragma clang loop unroll(disable)
    for (int ks = 0; ks < KSTEPS; ++ks) {
        f16x8 ah[NMT], alo[NMT];
        #pragma unroll
        for (int h = 0; h < NMT; ++h) {
            const int i = ((MTB+h)*KSTEPS + ks)*128 + lane;
            ah[h]  = afrag[i];
            alo[h] = afrag[i + 64];
        }
        #pragma unroll
        for (int nt = 0; nt < 4; ++nt) {
            const int fi = ((ntg0+nt)*KSTEPS + ks)*128 + lane;
            f16x8 bh = pfrag[fi];
            f16x8 bl = pfrag[fi + 64];
            #pragma unroll
            for (int h = 0; h < NMT; ++h) {
                acc[h][nt] = MFMA16(ah[h],  bh, acc[h][nt], 0,0,0);
                acc[h][nt] = MFMA16(ah[h],  bl, acc[h][nt], 0,0,0);
                acc[h][nt] = MFMA16(alo[h], bh, acc[h][nt], 0,0,0);
            }
        }
    }

    #pragma unroll
    for (int h = 0; h < NMT; ++h) {
        const int mt   = MTB + h;
        const int mtp  = (mt < 7) ? mt : mt-7;
        const int voff = (mt < 7) ? 0 : 100;
        const int ab   = mtp*16 + rg*4;
        #pragma unroll
        for (int nt = 0; nt < 4; ++nt) {
            const float s2 = v2t + p2v[nt];
            #pragma unroll
            for (int r = 0; r < 4; ++r) {
                const int al = ab + r;
                if (al < 100) {
                    float d2 = fmaxf(fmaf(-2.f, acc[h][nt][r], s2), 0.f) * 0.01f;
                    int vlog = voff + al;
                    if (d2 < minD[nt]) { minD[nt] = d2; minI[nt] = vlog; }
                    if (al == 0) sopen[voff ? 1 : 0][(ntl0+nt)*16 + col] = d2;
                }
            }
        }
    }
}

// ---------------------------------------------------------------------------
// One block = one target t x 512 queries (N split across blockIdx.y).
// 8 waves x 4 N-tiles each; 4 M-sweeps -> same B-traffic as R12 without
// the 128-reg acc tile that spilled.
// ---------------------------------------------------------------------------
__global__ __launch_bounds__(512) void matcher_mfma(
    const float* __restrict__ ws,      // p2 / v2 / pfrag / afrag
    const float* __restrict__ plog,    // [1024][2]
    const float* __restrict__ ptyp,    // [1024][4]
    const float* __restrict__ clog,    // [1024][2]
    const int*   __restrict__ labels,  // [256]
    const int*   __restrict__ iscl,    // [256]
    const float* __restrict__ clw,     // [256]
    float* __restrict__ out)           // [2][1024][256] flat fp32
{
    __shared__ float redD[2048];                      // [ntl(32)][rg*16+col]
    __shared__ int   redI[2048];
    __shared__ float sopen[2][512];

    const int t    = blockIdx.x;
    const int nb   = blockIdx.y;        // 0..1, N-half
    const int tid  = threadIdx.x;
    const int lane = tid & 63;
    const int w    = tid >> 6;          // wave 0..7 -> local N-tiles w*4..w*4+3
    const int col  = lane & 15;
    const int rg   = lane >> 4;

    const int ntl0 = w*4;               // local N-tile base
    const int ntg0 = nb*32 + ntl0;      // global N-tile base

    const float v2t = ws[1024 + t];
    float p2v[4];
    #pragma unroll
    for (int nt = 0; nt < 4; ++nt) p2v[nt] = ws[(ntg0+nt)*16 + col];

    const f16x8* __restrict__ pfrag = (const f16x8*)(ws + WS_PF);
    const f16x8* __restrict__ afrag = (const f16x8*)(ws + WS_AF) + t*AFRAG_PER_T;

    float minD[4]; int minI[4];
    #pragma unroll
    for (int nt = 0; nt < 4; ++nt) { minD[nt] = 3.4028235e38f; minI[nt] = 0; }

    sweep< 0,4>(afrag, pfrag, ntg0, lane, col, rg, v2t, p2v, minD, minI, sopen, ntl0);
    sweep< 4,4>(afrag, pfrag, ntg0, lane, col, rg, v2t, p2v, minD, minI, sopen, ntl0);
    sweep< 8,4>(afrag, pfrag, ntg0, lane, col, rg, v2t, p2v, minD, minI, sopen, ntl0);
    sweep<12,2>(afrag, pfrag, ntg0, lane, col, rg, v2t, p2v, minD, minI, sopen, ntl0);

    #pragma unroll
    for (int nt = 0; nt < 4; ++nt) {
        redD[(ntl0+nt)*64 + lane] = minD[nt];
        redI[(ntl0+nt)*64 + lane] = minI[nt];
    }
    __syncthreads();

    // Epilogue: one thread per local query (512).
    {
        const int lq   = tid;
        const int tile = lq >> 4;
        const int cc   = lq & 15;
        const int base = tile*64 + cc;
        float bd = redD[base]; int bi = redI[base];
        #pragma unroll
        for (int g = 1; g < 4; ++g) {
            float d = redD[base + g*16]; int i = redI[base + g*16];
            if (d < bd || (d == bd && i < bi)) { bd = d; bi = i; }
        }
        const int q = nb*512 + lq;
        int mapped = (bi <= NPTS-1) ? bi : (2*NPTS-1 - bi);
        float od   = fminf(sopen[0][lq], sopen[1][lq]);
        int   isc  = iscl[t];
        float geom = isc ? bd : od;
        int   ido  = isc ? mapped : 0;
        geom *= clw[t];

        float t0 = ptyp[q*4+0], t1 = ptyp[q*4+1];
        float t2 = ptyp[q*4+2], t3 = ptyp[q*4+3];
        float mx = fmaxf(fmaxf(t0,t1), fmaxf(t2,t3));
        float e0 = expf(t0-mx), e1 = expf(t1-mx), e2 = expf(t2-mx), e3 = expf(t3-mx);
        float rs = 1.0f/(e0+e1+e2+e3);
        int lab  = labels[t];
        float el = (lab == 0) ? e0 : (lab == 1) ? e1 : (lab == 2) ? e2 : e3;
        float cost = -logf(el*rs + EPSV);
        float v0 = plog[q*2+0], v1 = plog[q*2+1];
        cost += -logf(1.0f/(1.0f + expf(v1-v0)) + EPSV);
        float c0 = clog[q*2+0], c1 = clog[q*2+1];
        float pc = isc ? (1.0f/(1.0f + expf(c0-c1))) : (1.0f/(1.0f + expf(c1-c0)));
        cost += -logf(pc + EPSV);

        float C = geom + cost;
        out[q*T_TOT + t]               = C;
        out[Q_TOT*T_TOT + q*T_TOT + t] = (float)ido;
    }
}

extern "C" void kernel_launch(void* const* d_in, const int* in_sizes, int n_in,
                              void* d_out, int out_size, void* d_ws, size_t ws_size,
                              hipStream_t stream)
{
    const float* preds  = (const float*)d_in[0];  // pred_curve_points (1,1024,100,3)
    const float* plog   = (const float*)d_in[1];  // pred_curve_logits (1,1024,2)
    const float* ptyp   = (const float*)d_in[2];  // pred_curve_type   (1,1024,4)
    const float* clog   = (const float*)d_in[3];  // closed_curve_logits (1,1024,2)
    const float* tgt    = (const float*)d_in[4];  // tgt_curve_points  (256,100,3)
    const int*   labels = (const int*)d_in[5];    // tgt_labels (256)
    const int*   iscl   = (const int*)d_in[6];    // tgt_is_closed (256)
    const float* clw    = (const float*)d_in[7];  // curve_length_weighting (256)
    float* out = (float*)d_out;
    float* ws  = (float*)d_ws;    // ≈ 74.7 MB

    prep_all    <<<dim3(T_TOT),    dim3(512), 0, stream>>>(preds, tgt, ws);
    matcher_mfma<<<dim3(T_TOT, 2), dim3(512), 0, stream>>>(
        ws, plog, ptyp, clog, labels, iscl, clw, out);
}

// Round 17
// 170.744 us; speedup vs baseline: 1.2699x; 1.1661x over previous
//
#include <hip/hip_runtime.h>
#include <hip/hip_fp16.h>

#define Q_TOT 1024
#define T_TOT 256
#define NPTS  100
#define KD    300
#define EPSV  1e-6f

#define KSTEPS 10            // 10 * 32 = 320 >= 300 (zero-padded K)
#define EXTOFF 40            // front zero-pad for padded rows
#define EXTLEN 672           // f16 units per rotated copy

typedef _Float16 f16;
typedef _Float16 f16x8 __attribute__((ext_vector_type(8)));
typedef float    f32x4 __attribute__((ext_vector_type(4)));
#define MFMA16 __builtin_amdgcn_mfma_f32_16x16x32_f16

// ws layout (floats): [0,1024) p2[q]; [1024,1280) v2[t]; [1280,+327680) pfrag
#define WS_PF 1280

// ---------------------------------------------------------------------------
// Prep (tiny): each thread one pfrag f16x8; each wave one p2/v2 row via
// shuffle (argmin-safe reorder: p2+v2 is common-mode per (t,q) pair).
// Verified in R15/R16: absmax 0.03 << 1.98.
// ---------------------------------------------------------------------------
__global__ __launch_bounds__(256) void prep_all(const float* __restrict__ preds,
                                                const float* __restrict__ tgt,
                                                float* __restrict__ ws)
{
    const int i = blockIdx.x*256 + threadIdx.x;      // exactly 81920 threads
    {
        int lane = i & 63;
        int r    = i >> 6;
        int s    = r & 1;  r >>= 1;
        int ks   = r % KSTEPS;
        int nt   = r / KSTEPS;
        int q    = nt*16 + (lane & 15);
        int kb   = ks*32 + (lane >> 4)*8;
        f16x8 v;
        #pragma unroll
        for (int j = 0; j < 8; ++j) {
            int k = kb + j;
            float x = (k < KD) ? preds[q*KD + k] : 0.f;
            f16 h = (f16)x;
            v[j] = s ? (f16)(x - (float)h) : h;
        }
        ((f16x8*)(ws + WS_PF))[i] = v;
    }
    const int row  = blockIdx.x*4 + (threadIdx.x >> 6);   // 320*4 = 1280 rows
    const int lane = threadIdx.x & 63;
    const float* base = (row < 1024) ? preds + row*KD : tgt + (row-1024)*KD;
    float s = 0.f;
    for (int k = lane; k < KD; k += 64) s = fmaf(base[k], base[k], s);
    #pragma unroll
    for (int m = 1; m < 64; m <<= 1) s += __shfl_xor(s, m, 64);
    if (lane == 0) ws[row] = s;
}

// ---------------------------------------------------------------------------
// One sweep: NMT M-tiles x 4 N-tiles (acc 64 regs -- the proven no-spill
// level).  A-fragments via aligned ds_read_b128 from 8x byte-rotated LDS ext
// copies (R10-verified addressing); B via L2-resident global pfrag.
// ---------------------------------------------------------------------------
template<int MTB, int NMT>
__device__ __forceinline__ void sweep(const f16 (*sext)[8][EXTLEN],
                                      const f16x8* __restrict__ pfrag,
                                      int ntg0, int lane, int col, int rg, int cA,
                                      float v2t, const float (&p2v)[4],
                                      float (&minD)[4], int (&minI)[4],
                                      float (*sopen)[512], int ntl0)
{
    f32x4 acc[NMT][4];
    #pragma unroll
    for (int h = 0; h < NMT; ++h)
        #pragma unroll
        for (int nt = 0; nt < 4; ++nt) acc[h][nt] = (f32x4){0.f,0.f,0.f,0.f};

    #pragma clang loop unroll(disable)
    for (int ks = 0; ks < KSTEPS; ++ks) {
        f16x8 ah[NMT], alo[NMT];
        #pragma unroll
        for (int h = 0; h < NMT; ++h) {
            const int mt  = MTB + h;                   // compile-time
            const int mtp = (mt < 7) ? mt : mt-7;
            const int sel = (mt < 7) ? 0 : 2;
            const int idx = EXTOFF + 300 - 48*mtp - 3*col + 8*rg - cA + 32*ks;
            ah[h]  = *(const f16x8*)&sext[sel  ][cA][idx];
            alo[h] = *(const f16x8*)&sext[sel+1][cA][idx];
        }
        #pragma unroll
        for (int nt = 0; nt < 4; ++nt) {
            const int fi = ((ntg0+nt)*KSTEPS + ks)*128 + lane;
            f16x8 bh = pfrag[fi];
            f16x8 bl = pfrag[fi + 64];
            #pragma unroll
            for (int h = 0; h < NMT; ++h) {
                acc[h][nt] = MFMA16(ah[h],  bh, acc[h][nt], 0,0,0);
                acc[h][nt] = MFMA16(ah[h],  bl, acc[h][nt], 0,0,0);
                acc[h][nt] = MFMA16(alo[h], bh, acc[h][nt], 0,0,0);
            }
        }
    }

    #pragma unroll
    for (int h = 0; h < NMT; ++h) {
        const int mt   = MTB + h;
        const int mtp  = (mt < 7) ? mt : mt-7;
        const int voff = (mt < 7) ? 0 : 100;
        const int ab   = mtp*16 + rg*4;
        #pragma unroll
        for (int nt = 0; nt < 4; ++nt) {
            const float s2 = v2t + p2v[nt];
            #pragma unroll
            for (int r = 0; r < 4; ++r) {
                const int al = ab + r;
                if (al < 100) {
                    float d2 = fmaxf(fmaf(-2.f, acc[h][nt][r], s2), 0.f) * 0.01f;
                    int vlog = voff + al;
                    if (d2 < minD[nt]) { minD[nt] = d2; minI[nt] = vlog; }
                    if (al == 0) sopen[voff ? 1 : 0][(ntl0+nt)*16 + col] = d2;
                }
            }
        }
    }
}

// ---------------------------------------------------------------------------
// One block = one target t x 512 queries (blockIdx.y halves N).  8 waves x
// 4 N-tiles.  LDS: sext 43K + red 16K + sopen 4K = 63 KB -> 2 blocks/CU.
// ---------------------------------------------------------------------------
__global__ __launch_bounds__(512) void matcher_mfma(
    const float* __restrict__ ws,      // p2 / v2 / pfrag
    const float* __restrict__ tgt,     // [256][300]
    const float* __restrict__ plog,    // [1024][2]
    const float* __restrict__ ptyp,    // [1024][4]
    const float* __restrict__ clog,    // [1024][2]
    const int*   __restrict__ labels,  // [256]
    const int*   __restrict__ iscl,    // [256]
    const float* __restrict__ clw,     // [256]
    float* __restrict__ out)           // [2][1024][256] flat fp32
{
    __shared__ __align__(16) f16 sext[4][8][EXTLEN];  // {Fh,Fl,Rh,Rl} x 8 copies
    __shared__ float redD[2048];
    __shared__ int   redI[2048];
    __shared__ float sopen[2][512];

    const int t    = blockIdx.x;
    const int nb   = blockIdx.y;        // 0..1
    const int tid  = threadIdx.x;
    const int lane = tid & 63;
    const int w    = tid >> 6;
    const int col  = lane & 15;
    const int rg   = lane >> 4;
    const int ntl0 = w*4;
    const int ntg0 = nb*32 + ntl0;

    // Stage ext (fwd+rev, hi+lo split, 8 byte-rotated copies) -- R10-verified.
    const float* tg = tgt + t*KD;
    for (int x = tid; x < EXTLEN; x += 512) {
        int e = x - EXTOFF;
        float vF = 0.f, vR = 0.f;
        if (e >= 0 && e < 600) {
            int m = (e >= 300) ? e - 300 : e;
            vF = tg[m];
            int jj = m / 3, c3 = m - 3*jj;
            vR = tg[(NPTS-1-jj)*3 + c3];
        }
        f16 fh = (f16)vF, fl = (f16)(vF - (float)fh);
        f16 rh = (f16)vR, rl = (f16)(vR - (float)rh);
        #pragma unroll
        for (int c = 0; c < 8; ++c) {
            int y = x - c;
            if (y >= 0) {
                sext[0][c][y] = fh; sext[1][c][y] = fl;
                sext[2][c][y] = rh; sext[3][c][y] = rl;
            }
        }
    }

    const float v2t = ws[1024 + t];
    float p2v[4];
    #pragma unroll
    for (int nt = 0; nt < 4; ++nt) p2v[nt] = ws[(ntg0+nt)*16 + col];
    const f16x8* __restrict__ pfrag = (const f16x8*)(ws + WS_PF);
    const int cA = (EXTOFF + 300 - 3*col) & 7;   // rotation copy (lane-fixed)
    __syncthreads();

    float minD[4]; int minI[4];
    #pragma unroll
    for (int nt = 0; nt < 4; ++nt) { minD[nt] = 3.4028235e38f; minI[nt] = 0; }

    sweep< 0,4>(sext, pfrag, ntg0, lane, col, rg, cA, v2t, p2v, minD, minI, sopen, ntl0);
    sweep< 4,4>(sext, pfrag, ntg0, lane, col, rg, cA, v2t, p2v, minD, minI, sopen, ntl0);
    sweep< 8,4>(sext, pfrag, ntg0, lane, col, rg, cA, v2t, p2v, minD, minI, sopen, ntl0);
    sweep<12,2>(sext, pfrag, ntg0, lane, col, rg, cA, v2t, p2v, minD, minI, sopen, ntl0);

    #pragma unroll
    for (int nt = 0; nt < 4; ++nt) {
        redD[(ntl0+nt)*64 + lane] = minD[nt];
        redI[(ntl0+nt)*64 + lane] = minI[nt];
    }
    __syncthreads();

    // Epilogue: one thread per local query (R16-verified).
    {
        const int lq   = tid;
        const int tile = lq >> 4;
        const int cc   = lq & 15;
        const int base = tile*64 + cc;
        float bd = redD[base]; int bi = redI[base];
        #pragma unroll
        for (int g = 1; g < 4; ++g) {
            float d = redD[base + g*16]; int i = redI[base + g*16];
            if (d < bd || (d == bd && i < bi)) { bd = d; bi = i; }
        }
        const int q = nb*512 + lq;
        int mapped = (bi <= NPTS-1) ? bi : (2*NPTS-1 - bi);
        float od   = fminf(sopen[0][lq], sopen[1][lq]);
        int   isc  = iscl[t];
        float geom = isc ? bd : od;
        int   ido  = isc ? mapped : 0;
        geom *= clw[t];

        float t0 = ptyp[q*4+0], t1 = ptyp[q*4+1];
        float t2 = ptyp[q*4+2], t3 = ptyp[q*4+3];
        float mx = fmaxf(fmaxf(t0,t1), fmaxf(t2,t3));
        float e0 = expf(t0-mx), e1 = expf(t1-mx), e2 = expf(t2-mx), e3 = expf(t3-mx);
        float rs = 1.0f/(e0+e1+e2+e3);
        int lab  = labels[t];
        float el = (lab == 0) ? e0 : (lab == 1) ? e1 : (lab == 2) ? e2 : e3;
        float cost = -logf(el*rs + EPSV);
        float v0 = plog[q*2+0], v1 = plog[q*2+1];
        cost += -logf(1.0f/(1.0f + expf(v1-v0)) + EPSV);
        float c0 = clog[q*2+0], c1 = clog[q*2+1];
        float pc = isc ? (1.0f/(1.0f + expf(c0-c1))) : (1.0f/(1.0f + expf(c1-c0)));
        cost += -logf(pc + EPSV);

        float C = geom + cost;
        out[q*T_TOT + t]               = C;
        out[Q_TOT*T_TOT + q*T_TOT + t] = (float)ido;
    }
}

extern "C" void kernel_launch(void* const* d_in, const int* in_sizes, int n_in,
                              void* d_out, int out_size, void* d_ws, size_t ws_size,
                              hipStream_t stream)
{
    const float* preds  = (const float*)d_in[0];  // pred_curve_points (1,1024,100,3)
    const float* plog   = (const float*)d_in[1];  // pred_curve_logits (1,1024,2)
    const float* ptyp   = (const float*)d_in[2];  // pred_curve_type   (1,1024,4)
    const float* clog   = (const float*)d_in[3];  // closed_curve_logits (1,1024,2)
    const float* tgt    = (const float*)d_in[4];  // tgt_curve_points  (256,100,3)
    const int*   labels = (const int*)d_in[5];    // tgt_labels (256)
    const int*   iscl   = (const int*)d_in[6];    // tgt_is_closed (256)
    const float* clw    = (const float*)d_in[7];  // curve_length_weighting (256)
    float* out = (float*)d_out;
    float* ws  = (float*)d_ws;    // 1280 + 327680 floats = 1.32 MB

    prep_all    <<<dim3(320),      dim3(256), 0, stream>>>(preds, tgt, ws);
    matcher_mfma<<<dim3(T_TOT, 2), dim3(512), 0, stream>>>(
        ws, tgt, plog, ptyp, clog, labels, iscl, clw, out);
}